// Round 8
// baseline (219.039 us; speedup 1.0000x reference)
//
#include <hip/hip_runtime.h>
#include <math.h>

#define TN 2048
#define DN 1024
#define NEG_INF (-3.0e38f)

typedef __attribute__((ext_vector_type(8))) _Float16 half8;
typedef __attribute__((ext_vector_type(4))) _Float16 half4v;
typedef __attribute__((ext_vector_type(2))) _Float16 half2v;
typedef __attribute__((ext_vector_type(4))) float f32x4;

__device__ __forceinline__ f32x4 mfma16(half8 a, half8 b, f32x4 c) {
  return __builtin_amdgcn_mfma_f32_16x16x32_f16(a, b, c, 0, 0, 0);
}

// lgkm-only barrier (async staging survives); BAR_ALL drains vmcnt too.
#define BAR_LDS()  asm volatile("s_waitcnt lgkmcnt(0)\ns_barrier" ::: "memory")
#define BAR_ALL()  asm volatile("s_waitcnt vmcnt(0) lgkmcnt(0)\ns_barrier" ::: "memory")

// Tile image layout (32 keys x 1024 feats, f16, 64KB):
//   elem_off(key,f) = (f>>4)*512 + perm(key>>2)*64 + (key&3)*16 + (f&15)
//   perm(kg) = (kg&1)*4 + (kg>>1)   (tr_read lane-group lg sees keys 8*lg+j)
__device__ __forceinline__ int img_off(int key, int f) {
  const int kg = key >> 2;
  const int p  = ((kg & 1) << 2) | (kg >> 1);
  return (f >> 4) * 512 + p * 64 + (key & 3) * 16 + (f & 15);
}

// x fp32 [8][2048][1024] -> f16 tile images in ws: [b*64+tile][32768 elems]
__global__ __launch_bounds__(256) void convert_x(const float* __restrict__ x,
                                                 _Float16* __restrict__ w) {
  const long long gid = (long long)blockIdx.x * 256 + threadIdx.x;
  const long long e   = gid * 8;
  const int bt   = (int)(e >> 15);
  const int et   = (int)(e & 32767);
  const int f16b = et >> 9;
  const int p    = (et >> 6) & 7;
  const int row  = (et >> 4) & 3;
  const int col0 = et & 15;
  const int kg   = ((p & 3) << 1) | (p >> 2);    // inverse perm
  const int key  = kg * 4 + row;
  const size_t xoff = ((size_t)bt * 32 + key) * DN + f16b * 16 + col0;
  float4 u0 = *(const float4*)(x + xoff);
  float4 u1 = *(const float4*)(x + xoff + 4);
  half8 h = {(_Float16)u0.x, (_Float16)u0.y, (_Float16)u0.z, (_Float16)u0.w,
             (_Float16)u1.x, (_Float16)u1.y, (_Float16)u1.z, (_Float16)u1.w};
  *(half8*)(w + e) = h;
}

#define ISSUE4(T, O0, O1, O2, O3)                                             \
  asm volatile("ds_read_b64_tr_b16 %0, %4 offset:" O0 "\n\t"                  \
               "ds_read_b64_tr_b16 %1, %4 offset:" O1 "\n\t"                  \
               "ds_read_b64_tr_b16 %2, %4 offset:" O2 "\n\t"                  \
               "ds_read_b64_tr_b16 %3, %4 offset:" O3                         \
               : "=&v"(T[0]), "=&v"(T[1]), "=&v"(T[2]), "=&v"(T[3])           \
               : "v"(ab));

#define MFMA4(T, CT0, CT1)                                                    \
  {                                                                           \
    half8 bf0 = __builtin_shufflevector(T[0], T[1], 0, 1, 2, 3, 4, 5, 6, 7);  \
    half8 bf1 = __builtin_shufflevector(T[2], T[3], 0, 1, 2, 3, 4, 5, 6, 7);  \
    oacc[0][CT0] = mfma16(a0, bf0, oacc[0][CT0]);                             \
    oacc[1][CT0] = mfma16(a1, bf0, oacc[1][CT0]);                             \
    oacc[0][CT1] = mfma16(a0, bf1, oacc[0][CT1]);                             \
    oacc[1][CT1] = mfma16(a1, bf1, oacc[1][CT1]);                             \
  }

// One block = (batch, pair {pr,63-pr}) via hv loop -> 65 tiles/block.
// 8 waves, pure 8-way k-split (R7 geometry). NEW: 2-barrier pipelined
// schedule per tile:  P1 { rescale | QK(t+1) | PV(t) }  barLDS
//                     P3 { stage(t+2) issue ; SM(t+1) } barALL
// -> phases mix LDS/MFMA/VALU work and barrier count drops 3->2.
template <bool WS>
__global__ __launch_bounds__(512)
void attn_gate(const float* __restrict__ x, const _Float16* __restrict__ wsx,
               const float* __restrict__ pla, const float* __restrict__ pls,
               float* __restrict__ out) {
  __shared__ _Float16 Kbuf[2][32768];         // dbuf K tile images    128KB
  __shared__ _Float16 SredH[8][32][17][2];    // packed S partials     17.4KB
  __shared__ _Float16 Pq[32][40];             // P weights             2.5KB
  __shared__ float m_s[32], l_s[32], corr_s[32], gate_s[32];

  const int tid = threadIdx.x;
  const int w   = tid >> 6;       // wave 0..7 == kq (k-eighth, 128 feats)
  const int l   = tid & 63;
  const int lr  = l & 15;
  const int lg  = l >> 4;
  const int kq  = w;

  const int b  = blockIdx.x & 7;          // batch -> XCD
  const int pr = blockIdx.x >> 3;         // pair 0..31

  const float alpha = log1pf(expf(pla[0]));
  const float sigma = log1pf(expf(pls[0]));

  const float* xb = x + (size_t)b * TN * DN;
  float*       ob = out + (size_t)b * TN * DN;

  // QK B-frag bases (loop-invariant): keys lr and 16+lr
  const int kg0 = lr >> 2;
  const int bk0 = ((((kg0 & 1) << 2) | (kg0 >> 1)) << 6) + (lr & 3) * 16 + (lg & 1) * 8;
  const int kg1 = 4 + (lr >> 2);
  const int bk1 = ((((kg1 & 1) << 2) | (kg1 >> 1)) << 6) + (lr & 3) * 16 + (lg & 1) * 8;

  for (int hv = 0; hv < 2; ++hv) {
    const int qt    = hv ? (63 - pr) : pr;
    const int qbase = qt * 32;
    const int nkt   = qt + 1;

    // ---- helpers as lambdas (inlined) ----
    auto STAGE = [&](int t) {
      if constexpr (WS) {
        const _Float16* tn = wsx + (size_t)(b * 64 + t) * 32768;
#pragma unroll
        for (int i = 0; i < 8; ++i)
          __builtin_amdgcn_global_load_lds(
              (const __attribute__((address_space(1))) void*)(tn + w * 4096 + i * 512 + l * 8),
              (__attribute__((address_space(3))) void*)(&Kbuf[t & 1][w * 4096 + i * 512]), 16, 0, 0);
      } else {
        const int skey = tid >> 4, sc = tid & 15;
        const float* kp = xb + (size_t)(t * 32 + skey) * DN + sc * 4;
#pragma unroll
        for (int j = 0; j < 16; ++j) {
          const int f = sc * 4 + 64 * j;
          float4 v = *(const float4*)(kp + 64 * j);
          half4v h = {(_Float16)v.x, (_Float16)v.y, (_Float16)v.z, (_Float16)v.w};
          *(half4v*)&Kbuf[t & 1][img_off(skey, f)] = h;
        }
      }
    };

    // ---- stage tiles 0 (and 1) ----
    STAGE(0);
    if (nkt > 1) STAGE(1);

    // ---- Q fragments: BOTH row-tiles over k-eighth (2x4 half8 = 32 VGPR) ----
    half8 qf0[4], qf1[4];
    if constexpr (WS) {
      const _Float16* qtile = wsx + (size_t)(b * 64 + qt) * 32768;
      const int r0  = lr;
      const int g0  = r0 >> 2;
      const int qp0 = (((g0 & 1) << 2) | (g0 >> 1)) * 64 + (r0 & 3) * 16 + (lg & 1) * 8;
      const int r1  = 16 + lr;
      const int g1  = r1 >> 2;
      const int qp1 = (((g1 & 1) << 2) | (g1 >> 1)) * 64 + (r1 & 3) * 16 + (lg & 1) * 8;
#pragma unroll
      for (int s = 0; s < 4; ++s) {
        const int base = (kq * 8 + s * 2 + (lg >> 1)) * 512;
        qf0[s] = *(const half8*)&qtile[base + qp0];
        qf1[s] = *(const half8*)&qtile[base + qp1];
      }
    } else {
#pragma unroll
      for (int s = 0; s < 4; ++s) {
        const float* qp0 = xb + (size_t)(qbase + lr) * DN + kq * 128 + s * 32 + lg * 8;
        const float* qp1 = xb + (size_t)(qbase + 16 + lr) * DN + kq * 128 + s * 32 + lg * 8;
        float4 a = ((const float4*)qp0)[0];
        float4 c = ((const float4*)qp0)[1];
        half8 h0;
        h0[0]=(_Float16)a.x; h0[1]=(_Float16)a.y; h0[2]=(_Float16)a.z; h0[3]=(_Float16)a.w;
        h0[4]=(_Float16)c.x; h0[5]=(_Float16)c.y; h0[6]=(_Float16)c.z; h0[7]=(_Float16)c.w;
        qf0[s] = h0;
        a = ((const float4*)qp1)[0];
        c = ((const float4*)qp1)[1];
        half8 h1;
        h1[0]=(_Float16)a.x; h1[1]=(_Float16)a.y; h1[2]=(_Float16)a.z; h1[3]=(_Float16)a.w;
        h1[4]=(_Float16)c.x; h1[5]=(_Float16)c.y; h1[6]=(_Float16)c.z; h1[7]=(_Float16)c.w;
        qf1[s] = h1;
      }
    }

    f32x4 oacc[2][8];
#pragma unroll
    for (int rt = 0; rt < 2; ++rt)
#pragma unroll
      for (int ct = 0; ct < 8; ++ct)
        oacc[rt][ct] = f32x4{0.f, 0.f, 0.f, 0.f};

    if (tid < 32) { m_s[tid] = NEG_INF; l_s[tid] = 0.0f; }
    BAR_ALL();   // tiles 0/1 staged

    auto QK = [&](int t) {   // reads Kbuf[t&1], writes SredH
      f32x4 s00 = f32x4{0.f,0.f,0.f,0.f}, s01 = f32x4{0.f,0.f,0.f,0.f};
      f32x4 s10 = f32x4{0.f,0.f,0.f,0.f}, s11 = f32x4{0.f,0.f,0.f,0.f};
      const _Float16* kb = &Kbuf[t & 1][0];
#pragma unroll
      for (int s = 0; s < 4; ++s) {
        const int base = (kq * 8 + s * 2 + (lg >> 1)) * 512;
        half8 bf0 = *(const half8*)&kb[base + bk0];
        half8 bf1 = *(const half8*)&kb[base + bk1];
        s00 = mfma16(qf0[s], bf0, s00);
        s10 = mfma16(qf1[s], bf0, s10);
        s01 = mfma16(qf0[s], bf1, s01);
        s11 = mfma16(qf1[s], bf1, s11);
      }
#pragma unroll
      for (int j = 0; j < 4; ++j) {
        half2v p0 = {(_Float16)s00[j], (_Float16)s01[j]};
        *(half2v*)&SredH[kq][lg * 4 + j][lr][0] = p0;
        half2v p1 = {(_Float16)s10[j], (_Float16)s11[j]};
        *(half2v*)&SredH[kq][16 + lg * 4 + j][lr][0] = p1;
      }
    };

    auto SM = [&](int t) {   // reads SredH, writes Pq/m/l/corr
      const int r   = tid >> 4;
      const int c0  = tid & 15;
      const int qg  = qbase + r;
      const int kb0 = t * 32;
      float s0 = 0.f, s1 = 0.f;
#pragma unroll
      for (int k8 = 0; k8 < 8; ++k8) {
        half2v v = *(const half2v*)&SredH[k8][r][c0][0];
        s0 += (float)v[0];
        s1 += (float)v[1];
      }
      s0 *= 0.03125f; s1 *= 0.03125f;
      const bool v0 = (kb0 + c0)      < qg;
      const bool v1 = (kb0 + c0 + 16) < qg;
      if (!v0) s0 = NEG_INF;
      if (!v1) s1 = NEG_INF;
      float tmax = fmaxf(s0, s1);
#pragma unroll
      for (int d = 1; d < 16; d <<= 1) tmax = fmaxf(tmax, __shfl_xor(tmax, d));
      const float m_old = m_s[r];
      const float m_new = fmaxf(m_old, tmax);
      float p0 = v0 ? __expf(s0 - m_new) : 0.0f;
      float p1 = v1 ? __expf(s1 - m_new) : 0.0f;
      float ps = p0 + p1;
#pragma unroll
      for (int d = 1; d < 16; d <<= 1) ps += __shfl_xor(ps, d);
      if (c0 == 0) {
        const float corr = (m_old > 0.5f * NEG_INF) ? __expf(m_old - m_new) : 0.0f;
        m_s[r]    = m_new;
        l_s[r]    = l_s[r] * corr + ps;
        corr_s[r] = corr;
      }
      Pq[r][c0]      = (_Float16)p0;
      Pq[r][c0 + 16] = (_Float16)p1;
    };

    // ---- prologue: QK(0), SM(0) ----
    QK(0);
    BAR_LDS();
    SM(0);
    BAR_LDS();

    // ---- main pipelined loop: 2 barriers per tile ----
    for (int t = 0; t < nkt; ++t) {
      // P1: rescale | QK(t+1) | PV(t)
      {
        // per-row exact rescale skip: corr==1 <=> max unchanged
#pragma unroll
        for (int rt = 0; rt < 2; ++rt)
#pragma unroll
          for (int j = 0; j < 4; ++j) {
            const float cr2 = corr_s[rt * 16 + lg * 4 + j];
            if (cr2 < 1.0f) {
#pragma unroll
              for (int ct = 0; ct < 8; ++ct) oacc[rt][ct][j] *= cr2;
            }
          }
        if (t + 1 < nkt) QK(t + 1);     // independent of PV below

        const uint32_t pa0 = (uint32_t)(uintptr_t)(void*)&Pq[lr][lg * 8];
        const uint32_t pa1 = (uint32_t)(uintptr_t)(void*)&Pq[16 + lr][lg * 8];
        const uint32_t ab  = (uint32_t)(uintptr_t)(void*)&Kbuf[t & 1][w * 4096 + l * 4];
        // fence: all compiler LDS ops (incl. QK reads/Sred writes) drained
        asm volatile("s_waitcnt lgkmcnt(0)" ::: "memory");
        __builtin_amdgcn_sched_barrier(0);
        half8 a0, a1;
        half4v t0[4], t1[4];
        asm volatile("ds_read_b128 %0, %2\n\t"
                     "ds_read_b128 %1, %3"
                     : "=&v"(a0), "=&v"(a1) : "v"(pa0), "v"(pa1));
        ISSUE4(t0, "0", "512", "1024", "1536");
        ISSUE4(t1, "2048", "2560", "3072", "3584");
        asm volatile("s_waitcnt lgkmcnt(4)" ::: "memory");
        __builtin_amdgcn_sched_barrier(0);
        MFMA4(t0, 0, 1);
        ISSUE4(t0, "4096", "4608", "5120", "5632");
        asm volatile("s_waitcnt lgkmcnt(4)" ::: "memory");
        __builtin_amdgcn_sched_barrier(0);
        MFMA4(t1, 2, 3);
        ISSUE4(t1, "6144", "6656", "7168", "7680");
        asm volatile("s_waitcnt lgkmcnt(4)" ::: "memory");
        __builtin_amdgcn_sched_barrier(0);
        MFMA4(t0, 4, 5);
        asm volatile("s_waitcnt lgkmcnt(0)" ::: "memory");
        __builtin_amdgcn_sched_barrier(0);
        MFMA4(t1, 6, 7);
      }
      BAR_LDS();   // (1) PV(t)/QK(t+1) done; buf[t&1] free; Sred(t+1) ready

      // P3: stage(t+2) issue first, SM(t+1) hides its latency
      if (t + 2 < nkt) STAGE(t + 2);
      if (t + 1 < nkt) SM(t + 1);
      BAR_ALL();   // (2) staging drained; Pq(t+1)/corr(t+1) ready
    }

    // ---- epilogue: per-row <x,O>, |x|^2, |O|^2 (per-wave 128-feat slice) ----
    {
      float* ered = (float*)&SredH[0][0][0][0];   // reuse 4KB
#pragma unroll
      for (int rt = 0; rt < 2; ++rt)
#pragma unroll
        for (int j = 0; j < 4; ++j) {
          const int row = rt * 16 + lg * 4 + j;
          const float* xr = xb + (size_t)(qbase + row) * DN + w * 128 + lr;
          float a1 = 0.f, a2 = 0.f, a3 = 0.f;
#pragma unroll
          for (int ct = 0; ct < 8; ++ct) {
            const float xv = xr[ct * 16];
            const float ov = oacc[rt][ct][j];
            a1 += xv * ov; a2 += xv * xv; a3 += ov * ov;
          }
#pragma unroll
          for (int d = 1; d < 16; d <<= 1) {
            a1 += __shfl_xor(a1, d);
            a2 += __shfl_xor(a2, d);
            a3 += __shfl_xor(a3, d);
          }
          if (lr == 0) {
            float* e = ered + (row * 8 + w) * 4;
            e[0] = a1; e[1] = a2; e[2] = a3;
          }
        }
    }
    __syncthreads();
    if (tid < 32) {
      const float* ered = (const float*)&SredH[0][0][0][0];
      float SxO = 0.f, Sxx = 0.f, SOO = 0.f;
#pragma unroll
      for (int wv = 0; wv < 8; ++wv) {
        const float* e = ered + (tid * 8 + wv) * 4;
        SxO += e[0]; Sxx += e[1]; SOO += e[2];
      }
      const float lden = l_s[tid];
      float cosv = 0.0f;
      if (lden > 0.0f) {
        const float nx = fmaxf(sqrtf(Sxx), 1e-12f);
        const float nc = fmaxf(sqrtf(SOO) / lden, 1e-12f);
        cosv = (SxO / lden) / (nx * nc);
      }
      float nov = fminf(fmaxf(1.0f - cosv, 0.0f), 2.0f) * 0.5f;
      gate_s[tid] = 1.0f + alpha * tanhf(sigma * nov);
    }
    __syncthreads();
    {
#pragma unroll
      for (int rt = 0; rt < 2; ++rt)
#pragma unroll
        for (int j = 0; j < 4; ++j) {
          const int row = rt * 16 + lg * 4 + j;
          const float g = gate_s[row];
          const float* xr = xb + (size_t)(qbase + row) * DN + w * 128 + lr;
          float* orow     = ob + (size_t)(qbase + row) * DN + w * 128 + lr;
#pragma unroll
          for (int ct = 0; ct < 8; ++ct) {
            const float z = xr[ct * 16] * g;
            const float u = 0.7978845608028654f * (z + 0.044715f * z * z * z);
            orow[ct * 16] = 0.5f * z * (1.0f + tanhf(u));
          }
        }
    }
    __syncthreads();
  }
}

extern "C" void kernel_launch(void* const* d_in, const int* in_sizes, int n_in,
                              void* d_out, int out_size, void* d_ws, size_t ws_size,
                              hipStream_t stream) {
  const float* x  = (const float*)d_in[0];
  const float* la = (const float*)d_in[1];
  const float* ls = (const float*)d_in[2];
  float* out = (float*)d_out;
  const size_t need = (size_t)8 * 64 * 32768 * 2;   // 32 MB f16 tile images
  if (ws_size >= need) {
    convert_x<<<dim3(8192), dim3(256), 0, stream>>>(x, (_Float16*)d_ws);
    attn_gate<true><<<dim3(256), dim3(512), 0, stream>>>(
        x, (const _Float16*)d_ws, la, ls, out);
  } else {
    attn_gate<false><<<dim3(256), dim3(512), 0, stream>>>(
        x, (const _Float16*)nullptr, la, ls, out);
  }
}

// Round 9
// 213.529 us; speedup vs baseline: 1.0258x; 1.0258x over previous
//
#include <hip/hip_runtime.h>
#include <math.h>

#define TN 2048
#define DN 1024
#define NEG_INF (-3.0e38f)

typedef __attribute__((ext_vector_type(8))) _Float16 half8;
typedef __attribute__((ext_vector_type(4))) _Float16 half4v;
typedef __attribute__((ext_vector_type(2))) _Float16 half2v;
typedef __attribute__((ext_vector_type(4))) float f32x4;

__device__ __forceinline__ f32x4 mfma16(half8 a, half8 b, f32x4 c) {
  return __builtin_amdgcn_mfma_f32_16x16x32_f16(a, b, c, 0, 0, 0);
}

// lgkm-only barrier: staging (vmem) loads are NEVER drained at barriers.
#define BAR_LDS()  asm volatile("s_waitcnt lgkmcnt(0)\ns_barrier" ::: "memory")
// per-wave counted staging waits (segment-private K: no barrier needed)
#define WAITVM16() asm volatile("s_waitcnt vmcnt(16)" ::: "memory")
#define WAITVM0()  asm volatile("s_waitcnt vmcnt(0)" ::: "memory")

// Tile image layout (32 keys x 1024 feats, f16, 64KB):
//   elem_off(key,f) = (f>>4)*512 + perm(key>>2)*64 + (key&3)*16 + (f&15)
//   perm(kg) = (kg&1)*4 + (kg>>1)   (tr_read lane-group lg sees keys 8*lg+j)
// Segment property: elements [w*4096,(w+1)*4096) = feats [128w,128(w+1)) of
// all 32 keys. Wave w's QK reads, PV tr-reads AND staging writes all stay in
// its own segment -> K-tile sync is per-wave (vmcnt), not block-wide.
__device__ __forceinline__ int img_off(int key, int f) {
  const int kg = key >> 2;
  const int p  = ((kg & 1) << 2) | (kg >> 1);
  return (f >> 4) * 512 + p * 64 + (key & 3) * 16 + (f & 15);
}

// x fp32 [8][2048][1024] -> f16 tile images in ws: [b*64+tile][32768 elems]
__global__ __launch_bounds__(256) void convert_x(const float* __restrict__ x,
                                                 _Float16* __restrict__ w) {
  const long long gid = (long long)blockIdx.x * 256 + threadIdx.x;
  const long long e   = gid * 8;
  const int bt   = (int)(e >> 15);
  const int et   = (int)(e & 32767);
  const int f16b = et >> 9;
  const int p    = (et >> 6) & 7;
  const int row  = (et >> 4) & 3;
  const int col0 = et & 15;
  const int kg   = ((p & 3) << 1) | (p >> 2);    // inverse perm
  const int key  = kg * 4 + row;
  const size_t xoff = ((size_t)bt * 32 + key) * DN + f16b * 16 + col0;
  float4 u0 = *(const float4*)(x + xoff);
  float4 u1 = *(const float4*)(x + xoff + 4);
  half8 h = {(_Float16)u0.x, (_Float16)u0.y, (_Float16)u0.z, (_Float16)u0.w,
             (_Float16)u1.x, (_Float16)u1.y, (_Float16)u1.z, (_Float16)u1.w};
  *(half8*)(w + e) = h;
}

#define ISSUE4(T, O0, O1, O2, O3)                                             \
  asm volatile("ds_read_b64_tr_b16 %0, %4 offset:" O0 "\n\t"                  \
               "ds_read_b64_tr_b16 %1, %4 offset:" O1 "\n\t"                  \
               "ds_read_b64_tr_b16 %2, %4 offset:" O2 "\n\t"                  \
               "ds_read_b64_tr_b16 %3, %4 offset:" O3                         \
               : "=&v"(T[0]), "=&v"(T[1]), "=&v"(T[2]), "=&v"(T[3])           \
               : "v"(ab));

#define MFMA4(T, CT0, CT1)                                                    \
  {                                                                           \
    half8 bf0 = __builtin_shufflevector(T[0], T[1], 0, 1, 2, 3, 4, 5, 6, 7);  \
    half8 bf1 = __builtin_shufflevector(T[2], T[3], 0, 1, 2, 3, 4, 5, 6, 7);  \
    oacc[0][CT0] = mfma16(a0, bf0, oacc[0][CT0]);                             \
    oacc[1][CT0] = mfma16(a1, bf0, oacc[1][CT0]);                             \
    oacc[0][CT1] = mfma16(a0, bf1, oacc[0][CT1]);                             \
    oacc[1][CT1] = mfma16(a1, bf1, oacc[1][CT1]);                             \
  }

// One block = (batch, pair {pr,63-pr}) via hv loop -> 65 tiles/block.
// 8 waves, pure 8-way k-split. Schedule: per tile only TWO lgkm barriers
// (Sred, Pq); K staging is wave-private (segment property) and synced by
// counted s_waitcnt vmcnt(16) -> stage stays in flight a full iteration.
template <bool WS>
__global__ __launch_bounds__(512)
void attn_gate(const float* __restrict__ x, const _Float16* __restrict__ wsx,
               const float* __restrict__ pla, const float* __restrict__ pls,
               float* __restrict__ out) {
  __shared__ _Float16 Kbuf[2][32768];         // dbuf K tile images    128KB
  __shared__ _Float16 SredH[8][32][17][2];    // packed S partials     17.4KB
  __shared__ _Float16 Pq[32][40];             // P weights             2.5KB
  __shared__ float m_s[32], l_s[32], corr_s[32], gate_s[32];

  const int tid = threadIdx.x;
  const int w   = tid >> 6;       // wave 0..7 == kq (k-eighth, 128 feats)
  const int l   = tid & 63;
  const int lr  = l & 15;
  const int lg  = l >> 4;
  const int kq  = w;

  const int b  = blockIdx.x & 7;          // batch -> XCD
  const int pr = blockIdx.x >> 3;         // pair 0..31

  const float alpha = log1pf(expf(pla[0]));
  const float sigma = log1pf(expf(pls[0]));

  const float* xb = x + (size_t)b * TN * DN;
  float*       ob = out + (size_t)b * TN * DN;

  // QK B-frag bases (loop-invariant): keys lr and 16+lr
  const int kg0 = lr >> 2;
  const int bk0 = ((((kg0 & 1) << 2) | (kg0 >> 1)) << 6) + (lr & 3) * 16 + (lg & 1) * 8;
  const int kg1 = 4 + (lr >> 2);
  const int bk1 = ((((kg1 & 1) << 2) | (kg1 >> 1)) << 6) + (lr & 3) * 16 + (lg & 1) * 8;

  for (int hv = 0; hv < 2; ++hv) {
    const int qt    = hv ? (63 - pr) : pr;
    const int qbase = qt * 32;
    const int nkt   = qt + 1;

    auto STAGE = [&](int t) {   // wave w writes ONLY its own segment
      if constexpr (WS) {
        const _Float16* tn = wsx + (size_t)(b * 64 + t) * 32768;
#pragma unroll
        for (int i = 0; i < 8; ++i)
          __builtin_amdgcn_global_load_lds(
              (const __attribute__((address_space(1))) void*)(tn + w * 4096 + i * 512 + l * 8),
              (__attribute__((address_space(3))) void*)(&Kbuf[t & 1][w * 4096 + i * 512]), 16, 0, 0);
      } else {
        const int skey = tid >> 4, sc = tid & 15;
        const float* kp = xb + (size_t)(t * 32 + skey) * DN + sc * 4;
#pragma unroll
        for (int j = 0; j < 16; ++j) {
          const int f = sc * 4 + 64 * j;
          float4 v = *(const float4*)(kp + 64 * j);
          half4v h = {(_Float16)v.x, (_Float16)v.y, (_Float16)v.z, (_Float16)v.w};
          *(half4v*)&Kbuf[t & 1][img_off(skey, f)] = h;
        }
      }
    };

    // ---- stage tiles 0 (and 1) ----
    STAGE(0);
    if (nkt > 1) STAGE(1);

    // ---- Q fragments: BOTH row-tiles over k-eighth (2x4 half8 = 32 VGPR) ----
    half8 qf0[4], qf1[4];
    if constexpr (WS) {
      const _Float16* qtile = wsx + (size_t)(b * 64 + qt) * 32768;
      const int r0  = lr;
      const int g0  = r0 >> 2;
      const int qp0 = (((g0 & 1) << 2) | (g0 >> 1)) * 64 + (r0 & 3) * 16 + (lg & 1) * 8;
      const int r1  = 16 + lr;
      const int g1  = r1 >> 2;
      const int qp1 = (((g1 & 1) << 2) | (g1 >> 1)) * 64 + (r1 & 3) * 16 + (lg & 1) * 8;
#pragma unroll
      for (int s = 0; s < 4; ++s) {
        const int base = (kq * 8 + s * 2 + (lg >> 1)) * 512;
        qf0[s] = *(const half8*)&qtile[base + qp0];
        qf1[s] = *(const half8*)&qtile[base + qp1];
      }
    } else {
#pragma unroll
      for (int s = 0; s < 4; ++s) {
        const float* qp0 = xb + (size_t)(qbase + lr) * DN + kq * 128 + s * 32 + lg * 8;
        const float* qp1 = xb + (size_t)(qbase + 16 + lr) * DN + kq * 128 + s * 32 + lg * 8;
        float4 a = ((const float4*)qp0)[0];
        float4 c = ((const float4*)qp0)[1];
        half8 h0;
        h0[0]=(_Float16)a.x; h0[1]=(_Float16)a.y; h0[2]=(_Float16)a.z; h0[3]=(_Float16)a.w;
        h0[4]=(_Float16)c.x; h0[5]=(_Float16)c.y; h0[6]=(_Float16)c.z; h0[7]=(_Float16)c.w;
        qf0[s] = h0;
        a = ((const float4*)qp1)[0];
        c = ((const float4*)qp1)[1];
        half8 h1;
        h1[0]=(_Float16)a.x; h1[1]=(_Float16)a.y; h1[2]=(_Float16)a.z; h1[3]=(_Float16)a.w;
        h1[4]=(_Float16)c.x; h1[5]=(_Float16)c.y; h1[6]=(_Float16)c.z; h1[7]=(_Float16)c.w;
        qf1[s] = h1;
      }
    }

    f32x4 oacc[2][8];
#pragma unroll
    for (int rt = 0; rt < 2; ++rt)
#pragma unroll
      for (int ct = 0; ct < 8; ++ct)
        oacc[rt][ct] = f32x4{0.f, 0.f, 0.f, 0.f};

    if (tid < 32) { m_s[tid] = NEG_INF; l_s[tid] = 0.0f; }
    BAR_LDS();   // m/l init visible (no vmcnt drain: QK waits per-wave)

    for (int t = 0; t < nkt; ++t) {
      // ---- per-wave staging wait: stage(t) done, stage(t+1) in flight ----
      if (t + 1 < nkt) { WAITVM16(); } else { WAITVM0(); }

      // ---- QK^T: wave kq -> all four 16x16 S-tiles over its k-eighth ----
      {
        f32x4 s00 = f32x4{0.f,0.f,0.f,0.f}, s01 = f32x4{0.f,0.f,0.f,0.f};
        f32x4 s10 = f32x4{0.f,0.f,0.f,0.f}, s11 = f32x4{0.f,0.f,0.f,0.f};
        const _Float16* kb = &Kbuf[t & 1][0];
#pragma unroll
        for (int s = 0; s < 4; ++s) {
          const int base = (kq * 8 + s * 2 + (lg >> 1)) * 512;
          half8 bf0 = *(const half8*)&kb[base + bk0];
          half8 bf1 = *(const half8*)&kb[base + bk1];
          s00 = mfma16(qf0[s], bf0, s00);
          s10 = mfma16(qf1[s], bf0, s10);
          s01 = mfma16(qf0[s], bf1, s01);
          s11 = mfma16(qf1[s], bf1, s11);
        }
#pragma unroll
        for (int j = 0; j < 4; ++j) {
          half2v p0 = {(_Float16)s00[j], (_Float16)s01[j]};
          *(half2v*)&SredH[kq][lg * 4 + j][lr][0] = p0;
          half2v p1 = {(_Float16)s10[j], (_Float16)s11[j]};
          *(half2v*)&SredH[kq][16 + lg * 4 + j][lr][0] = p1;
        }
      }
      BAR_LDS();   // (A) SredH ready

      // ---- online softmax: 16 lanes per q-row ----
      {
        const int r   = tid >> 4;
        const int c0  = tid & 15;
        const int qg  = qbase + r;
        const int kb0 = t * 32;
        float s0 = 0.f, s1 = 0.f;
#pragma unroll
        for (int k8 = 0; k8 < 8; ++k8) {
          half2v v = *(const half2v*)&SredH[k8][r][c0][0];
          s0 += (float)v[0];
          s1 += (float)v[1];
        }
        s0 *= 0.03125f; s1 *= 0.03125f;
        const bool v0 = (kb0 + c0)      < qg;
        const bool v1 = (kb0 + c0 + 16) < qg;
        if (!v0) s0 = NEG_INF;
        if (!v1) s1 = NEG_INF;
        float tmax = fmaxf(s0, s1);
#pragma unroll
        for (int d = 1; d < 16; d <<= 1) tmax = fmaxf(tmax, __shfl_xor(tmax, d));
        const float m_old = m_s[r];
        const float m_new = fmaxf(m_old, tmax);
        float p0 = v0 ? __expf(s0 - m_new) : 0.0f;
        float p1 = v1 ? __expf(s1 - m_new) : 0.0f;
        float ps = p0 + p1;
#pragma unroll
        for (int d = 1; d < 16; d <<= 1) ps += __shfl_xor(ps, d);
        if (c0 == 0) {
          const float corr = (m_old > 0.5f * NEG_INF) ? __expf(m_old - m_new) : 0.0f;
          m_s[r]    = m_new;
          l_s[r]    = l_s[r] * corr + ps;
          corr_s[r] = corr;
        }
        Pq[r][c0]      = (_Float16)p0;
        Pq[r][c0 + 16] = (_Float16)p1;
      }
      BAR_LDS();   // (B) Pq/corr ready

      // ---- PV: per-row exact rescale skip, asm-pipelined tr_read + MFMA ----
      {
#pragma unroll
        for (int rt = 0; rt < 2; ++rt)
#pragma unroll
          for (int j = 0; j < 4; ++j) {
            const float cr2 = corr_s[rt * 16 + lg * 4 + j];
            if (cr2 < 1.0f) {
#pragma unroll
              for (int ct = 0; ct < 8; ++ct) oacc[rt][ct][j] *= cr2;
            }
          }
        const uint32_t pa0 = (uint32_t)(uintptr_t)(void*)&Pq[lr][lg * 8];
        const uint32_t pa1 = (uint32_t)(uintptr_t)(void*)&Pq[16 + lr][lg * 8];
        const uint32_t ab  = (uint32_t)(uintptr_t)(void*)&Kbuf[t & 1][w * 4096 + l * 4];
        // fence: no compiler LDS ops in flight inside the asm region
        asm volatile("s_waitcnt lgkmcnt(0)" ::: "memory");
        __builtin_amdgcn_sched_barrier(0);
        half8 a0, a1;
        half4v t0[4], t1[4];
        asm volatile("ds_read_b128 %0, %2\n\t"
                     "ds_read_b128 %1, %3"
                     : "=&v"(a0), "=&v"(a1) : "v"(pa0), "v"(pa1));
        ISSUE4(t0, "0", "512", "1024", "1536");
        ISSUE4(t1, "2048", "2560", "3072", "3584");
        asm volatile("s_waitcnt lgkmcnt(4)" ::: "memory");
        __builtin_amdgcn_sched_barrier(0);
        MFMA4(t0, 0, 1);
        ISSUE4(t0, "4096", "4608", "5120", "5632");
        asm volatile("s_waitcnt lgkmcnt(4)" ::: "memory");
        __builtin_amdgcn_sched_barrier(0);
        MFMA4(t1, 2, 3);
        ISSUE4(t1, "6144", "6656", "7168", "7680");
        asm volatile("s_waitcnt lgkmcnt(4)" ::: "memory");
        __builtin_amdgcn_sched_barrier(0);
        MFMA4(t0, 4, 5);
        asm volatile("s_waitcnt lgkmcnt(0)" ::: "memory");
        __builtin_amdgcn_sched_barrier(0);
        MFMA4(t1, 6, 7);
      }

      // ---- wave-private restage: own segment of buf[t&1], no barrier ----
      if (t + 2 < nkt) STAGE(t + 2);
    }

    // ---- epilogue: per-row <x,O>, |x|^2, |O|^2 (per-wave 128-feat slice) ----
    {
      float* ered = (float*)&SredH[0][0][0][0];   // reuse 4KB
#pragma unroll
      for (int rt = 0; rt < 2; ++rt)
#pragma unroll
        for (int j = 0; j < 4; ++j) {
          const int row = rt * 16 + lg * 4 + j;
          const float* xr = xb + (size_t)(qbase + row) * DN + w * 128 + lr;
          float a1 = 0.f, a2 = 0.f, a3 = 0.f;
#pragma unroll
          for (int ct = 0; ct < 8; ++ct) {
            const float xv = xr[ct * 16];
            const float ov = oacc[rt][ct][j];
            a1 += xv * ov; a2 += xv * xv; a3 += ov * ov;
          }
#pragma unroll
          for (int d = 1; d < 16; d <<= 1) {
            a1 += __shfl_xor(a1, d);
            a2 += __shfl_xor(a2, d);
            a3 += __shfl_xor(a3, d);
          }
          if (lr == 0) {
            float* e = ered + (row * 8 + w) * 4;
            e[0] = a1; e[1] = a2; e[2] = a3;
          }
        }
    }
    __syncthreads();
    if (tid < 32) {
      const float* ered = (const float*)&SredH[0][0][0][0];
      float SxO = 0.f, Sxx = 0.f, SOO = 0.f;
#pragma unroll
      for (int wv = 0; wv < 8; ++wv) {
        const float* e = ered + (tid * 8 + wv) * 4;
        SxO += e[0]; Sxx += e[1]; SOO += e[2];
      }
      const float lden = l_s[tid];
      float cosv = 0.0f;
      if (lden > 0.0f) {
        const float nx = fmaxf(sqrtf(Sxx), 1e-12f);
        const float nc = fmaxf(sqrtf(SOO) / lden, 1e-12f);
        cosv = (SxO / lden) / (nx * nc);
      }
      float nov = fminf(fmaxf(1.0f - cosv, 0.0f), 2.0f) * 0.5f;
      gate_s[tid] = 1.0f + alpha * tanhf(sigma * nov);
    }
    __syncthreads();
    {
#pragma unroll
      for (int rt = 0; rt < 2; ++rt)
#pragma unroll
        for (int j = 0; j < 4; ++j) {
          const int row = rt * 16 + lg * 4 + j;
          const float g = gate_s[row];
          const float* xr = xb + (size_t)(qbase + row) * DN + w * 128 + lr;
          float* orow     = ob + (size_t)(qbase + row) * DN + w * 128 + lr;
#pragma unroll
          for (int ct = 0; ct < 8; ++ct) {
            const float z = xr[ct * 16] * g;
            const float u = 0.7978845608028654f * (z + 0.044715f * z * z * z);
            orow[ct * 16] = 0.5f * z * (1.0f + tanhf(u));
          }
        }
    }
    __syncthreads();
  }
}

extern "C" void kernel_launch(void* const* d_in, const int* in_sizes, int n_in,
                              void* d_out, int out_size, void* d_ws, size_t ws_size,
                              hipStream_t stream) {
  const float* x  = (const float*)d_in[0];
  const float* la = (const float*)d_in[1];
  const float* ls = (const float*)d_in[2];
  float* out = (float*)d_out;
  const size_t need = (size_t)8 * 64 * 32768 * 2;   // 32 MB f16 tile images
  if (ws_size >= need) {
    convert_x<<<dim3(8192), dim3(256), 0, stream>>>(x, (_Float16*)d_ws);
    attn_gate<true><<<dim3(256), dim3(512), 0, stream>>>(
        x, (const _Float16*)d_ws, la, ls, out);
  } else {
    attn_gate<false><<<dim3(256), dim3(512), 0, stream>>>(
        x, (const _Float16*)nullptr, la, ls, out);
  }
}